// Round 19
// baseline (224.803 us; speedup 1.0000x reference)
//
#include <hip/hip_runtime.h>
#include <hip/hip_bf16.h>

#define LSEQ   2048
#define DK     64
#define NH     16
#define BS     2
#define DMODEL 1024
#define BH     (BS*NH)    // 32
#define MTOT   (BS*LSEQ)  // 4096

typedef __attribute__((ext_vector_type(8))) short bf16x8;
typedef __attribute__((ext_vector_type(4))) float f32x4;
typedef __attribute__((ext_vector_type(16))) float f32x16;

#define MFMA16(a,b,c) __builtin_amdgcn_mfma_f32_16x16x32_bf16((a),(b),(c),0,0,0)
#define MFMA32(a,b,c) __builtin_amdgcn_mfma_f32_32x32x16_bf16((a),(b),(c),0,0,0)
#define GLD_LDS(g,l) __builtin_amdgcn_global_load_lds((const __attribute__((address_space(1))) void*)(g), (__attribute__((address_space(3))) void*)(l), 16, 0, 0)

#define L2E   1.4426950408889634f      // log2(e)
#define L2E2  2.0813689810056077f      // log2(e)^2

__device__ __forceinline__ short f2bs(float f) {
  union { __hip_bfloat16 h; short s; } u; u.h = __float2bfloat16(f); return u.s;
}
__device__ __forceinline__ float b2f(unsigned short s) {
  union { unsigned u; float f; } v; v.u = ((unsigned)s) << 16; return v.f;
}
// cheap round-half-up bf16 (inputs guaranteed finite)
__device__ __forceinline__ unsigned short f2bs_c(float f) {
  union { float f; unsigned u; } v; v.f = f;
  return (unsigned short)((v.u + 0x8000u) >> 16);
}
__device__ __forceinline__ unsigned pk2c(float lo, float hi) {
  union { float f; unsigned u; } a, b; a.f = lo; b.f = hi;
  return ((a.u + 0x8000u) >> 16) | ((b.u + 0x8000u) & 0xffff0000u);
}
__device__ __forceinline__ unsigned pk2(float lo, float hi) {
  return (unsigned)(unsigned short)f2bs(lo) | (((unsigned)(unsigned short)f2bs(hi)) << 16);
}
// raw v_exp_f32 (2^x); VALU->VALU deps are HW-interlocked on CDNA
__device__ __forceinline__ float fexp2(float x) {
  float r; asm("v_exp_f32 %0, %1" : "=v"(r) : "v"(x)); return r;
}
__device__ __forceinline__ float fexp2n(float x) {   // 2^(-x), free input modifier
  float r; asm("v_exp_f32 %0, -%1" : "=v"(r) : "v"(x)); return r;
}
// single-instruction packed f32->bf16 (RNE)
__device__ __forceinline__ unsigned cvtpk(float lo, float hi) {
  unsigned r; asm("v_cvt_pk_bf16_f32 %0, %1, %2" : "=v"(r) : "v"(lo), "v"(hi)); return r;
}

// ---------------- fused converts: weight transposes + activations ----------------
// blocks 0..7167: f32 [K][N] -> bf16 [N][K] transposes (Wqm 3072, Wqs 3072, Wo 1024)
// blocks 7168..9215: flat f32 -> bf16 convert of mu|sigma (grid-stride, 2048 blocks)
__global__ __launch_bounds__(256) void cvt_all_k(
    const float* __restrict__ mu, const float* __restrict__ sigma,
    short* __restrict__ Amu, short* __restrict__ Asg,
    const float* __restrict__ Wqm, const float* __restrict__ Wqs, const float* __restrict__ Wo,
    short* __restrict__ Wqm_t, short* __restrict__ Wqs_t, short* __restrict__ Wo_t) {
  int id = blockIdx.x;
  int t = threadIdx.x;
  if (id >= 7168) {
    int n8 = MTOT * DMODEL / 8;
    int total = n8 * 2;
    for (int i = (id - 7168) * 256 + t; i < total; i += 2048 * 256) {
      int sel = i >= n8;
      int j = sel ? i - n8 : i;
      const float4* p = (const float4*)(sel ? sigma : mu) + (size_t)j * 2;
      float4 x = p[0], y = p[1];
      uint4 o;
      o.x = pk2(x.x, x.y); o.y = pk2(x.z, x.w);
      o.z = pk2(y.x, y.y); o.w = pk2(y.z, y.w);
      ((uint4*)(sel ? Asg : Amu))[j] = o;
    }
    return;
  }
  __shared__ float tile[32][33];
  const float* W; short* Wt; int Ncols, bx;
  if (id < 3072)      { W = Wqm; Wt = Wqm_t; Ncols = 3072; bx = id % 96; id /= 96; }
  else if (id < 6144) { id -= 3072; W = Wqs; Wt = Wqs_t; Ncols = 3072; bx = id % 96; id /= 96; }
  else                { id -= 6144; W = Wo;  Wt = Wo_t;  Ncols = 1024; bx = id % 32; id /= 32; }
  int n0 = bx * 32, k0 = id * 32;
#pragma unroll
  for (int i = 0; i < 4; ++i) {
    int idx = t + i * 256; int r = idx >> 5, c = idx & 31;
    tile[r][c] = W[(size_t)(k0 + r) * Ncols + n0 + c];
  }
  __syncthreads();
#pragma unroll
  for (int i = 0; i < 4; ++i) {
    int idx = t + i * 256; int r = idx >> 5, c = idx & 31;
    Wt[(size_t)(n0 + r) * 1024 + k0 + c] = f2bs(tile[c][r]);
  }
}

// ---------------- fused QKV GEMM (mu + sigma in ONE dispatch), 128x128 tile ----------------
// R19: grid TRANSPOSED to (48, 32): blockIdx.x = ny (n-panel), blockIdx.y = m.
// HW XCD = linear_id % 8 = blockIdx.x % 8 = ny % 8 -> each XCD keeps its 6
// B-panels (1.5MB of W*_t) L2-resident, fetched ONCE (B traffic 96 -> 12MB).
// A streams with ~3MB concurrent working set (mostly L2-hit).
__global__ __launch_bounds__(256) void qkv_gemm_k(
    const short* __restrict__ Amu, const short* __restrict__ Asg,
    const short* __restrict__ Wqm_t, const short* __restrict__ Wqs_t,
    const float* __restrict__ bqm, const float* __restrict__ bqs,
    short* __restrict__ Qm, short* __restrict__ Km, short* __restrict__ VmT,
    short* __restrict__ Qs, short* __restrict__ Ks, short* __restrict__ VsT) {
  __shared__ short As[128 * 64];
  __shared__ short Bs[128 * 64];
  int ny = blockIdx.x;                 // 0..47; >=24 -> sigma set
  int sg = ny >= 24;
  int n0 = (sg ? ny - 24 : ny) * 128;
  const short* A  = sg ? Asg : Amu;
  const short* Bt = sg ? Wqs_t : Wqm_t;
  const float* bias = sg ? bqs : bqm;
  short* Qb  = sg ? Qs : Qm;
  short* Kb  = sg ? Ks : Km;
  short* VTb = sg ? VsT : VmT;

  int tid = threadIdx.x, w = tid >> 6, ln = tid & 63, lg = ln >> 4, lr = ln & 15;
  int m0 = blockIdx.y * 128;
  int wr = w >> 1, wc = w & 1;
  f32x4 acc[4][4] = {};

  for (int k0 = 0; k0 < 1024; k0 += 64) {
    __syncthreads();
#pragma unroll
    for (int i = 0; i < 4; ++i) {
      int cb = w * 64 + i * 256;
      int c = cb + ln;
      GLD_LDS(A  + (size_t)(m0 + (c >> 3)) * 1024 + k0 + (c & 7) * 8, &As[cb * 8]);
      GLD_LDS(Bt + (size_t)(n0 + (c >> 3)) * 1024 + k0 + (c & 7) * 8, &Bs[cb * 8]);
    }
    __syncthreads();
#pragma unroll
    for (int kh = 0; kh < 2; ++kh) {
      bf16x8 af[4], bfr[4];
#pragma unroll
      for (int mi = 0; mi < 4; ++mi)
        af[mi] = *(const bf16x8*)&As[(wr * 64 + mi * 16 + lr) * 64 + kh * 32 + lg * 8];
#pragma unroll
      for (int ni = 0; ni < 4; ++ni)
        bfr[ni] = *(const bf16x8*)&Bs[(wc * 64 + ni * 16 + lr) * 64 + kh * 32 + lg * 8];
#pragma unroll
      for (int mi = 0; mi < 4; ++mi)
#pragma unroll
        for (int ni = 0; ni < 4; ++ni)
          acc[mi][ni] = MFMA16(af[mi], bfr[ni], acc[mi][ni]);
    }
  }

#pragma unroll
  for (int ni = 0; ni < 4; ++ni) {
    int n = n0 + wc * 64 + ni * 16 + lr;
    float bv = bias[n];
    int part = n >> 10, cc = n & 1023, hh = cc >> 6, dd = cc & 63;
#pragma unroll
    for (int mi = 0; mi < 4; ++mi) {
      int mbase = m0 + wr * 64 + mi * 16 + 4 * lg;
      float vv[4];
#pragma unroll
      for (int r = 0; r < 4; ++r) vv[r] = acc[mi][ni][r] + bv;
      if (part == 2) {
        int b = mbase >> 11, tok = mbase & 2047, bh = b * NH + hh;
        uint2 pk; pk.x = pk2c(vv[0], vv[1]); pk.y = pk2c(vv[2], vv[3]);
        *(uint2*)&VTb[((size_t)bh * DK + dd) * LSEQ + tok] = pk;
      } else {
        short* dst = (part == 0) ? Qb : Kb;
#pragma unroll
        for (int r = 0; r < 4; ++r) {
          int m = mbase + r;
          int b = m >> 11, tok = m & 2047, bh = b * NH + hh;
          dst[((size_t)bh * LSEQ + tok) * DK + dd] = (short)f2bs_c(vv[r]);
        }
      }
    }
  }
}

// ---------------- 128x128-tile bf16 GEMM (out-proj, f32 out) ----------------
__global__ __launch_bounds__(256) void gemm128_k(
    const short* __restrict__ A, const short* __restrict__ Bt,
    const float* __restrict__ bias, float* __restrict__ outF) {
  __shared__ short As[128 * 64];
  __shared__ short Bs[128 * 64];
  int tid = threadIdx.x, w = tid >> 6, ln = tid & 63, lg = ln >> 4, lr = ln & 15;
  int m0 = blockIdx.x * 128, n0 = blockIdx.y * 128;
  int wr = w >> 1, wc = w & 1;
  f32x4 acc[4][4] = {};

  for (int k0 = 0; k0 < 1024; k0 += 64) {
    __syncthreads();
#pragma unroll
    for (int i = 0; i < 4; ++i) {
      int cb = w * 64 + i * 256;
      int c = cb + ln;
      GLD_LDS(A  + (size_t)(m0 + (c >> 3)) * 1024 + k0 + (c & 7) * 8, &As[cb * 8]);
      GLD_LDS(Bt + (size_t)(n0 + (c >> 3)) * 1024 + k0 + (c & 7) * 8, &Bs[cb * 8]);
    }
    __syncthreads();
#pragma unroll
    for (int kh = 0; kh < 2; ++kh) {
      bf16x8 af[4], bfr[4];
#pragma unroll
      for (int mi = 0; mi < 4; ++mi)
        af[mi] = *(const bf16x8*)&As[(wr * 64 + mi * 16 + lr) * 64 + kh * 32 + lg * 8];
#pragma unroll
      for (int ni = 0; ni < 4; ++ni)
        bfr[ni] = *(const bf16x8*)&Bs[(wc * 64 + ni * 16 + lr) * 64 + kh * 32 + lg * 8];
#pragma unroll
      for (int mi = 0; mi < 4; ++mi)
#pragma unroll
        for (int ni = 0; ni < 4; ++ni)
          acc[mi][ni] = MFMA16(af[mi], bfr[ni], acc[mi][ni]);
    }
  }

#pragma unroll
  for (int ni = 0; ni < 4; ++ni) {
    int n = n0 + wc * 64 + ni * 16 + lr;
    float bv = bias[n];
#pragma unroll
    for (int mi = 0; mi < 4; ++mi) {
      int mbase = m0 + wr * 64 + mi * 16 + 4 * lg;
#pragma unroll
      for (int r = 0; r < 4; ++r)
        outF[(size_t)(mbase + r) * 1024 + n] = acc[mi][ni][r] + bv;
    }
  }
}

// ---------------- per-row squared norms (pre-scaled by log2(e)^2) ----------------
__global__ __launch_bounds__(256) void norms_k(
    const short* __restrict__ Qm, const short* __restrict__ Qs,
    const short* __restrict__ Km, const short* __restrict__ Ks,
    float* __restrict__ sqq, float* __restrict__ sqk) {
  int id = blockIdx.x * 256 + threadIdx.x;  // 0..131071
  int row = id & 65535;
  const short* p1 = (id < 65536) ? Qm : Km;
  const short* p2 = (id < 65536) ? Qs : Ks;
  float* outp = (id < 65536) ? sqq : sqk;
  const uint4* a = (const uint4*)(p1 + (size_t)row * DK);
  const uint4* b = (const uint4*)(p2 + (size_t)row * DK);
  float s = 0.f;
#pragma unroll
  for (int i = 0; i < 8; ++i) {
    uint4 x = a[i], y = b[i];
    unsigned vx[4] = {x.x, x.y, x.z, x.w};
    unsigned vy[4] = {y.x, y.y, y.z, y.w};
#pragma unroll
    for (int j = 0; j < 4; ++j) {
      float l1 = b2f((unsigned short)(vx[j] & 0xffff)), h1 = b2f((unsigned short)(vx[j] >> 16));
      float l2 = b2f((unsigned short)(vy[j] & 0xffff)), h2 = b2f((unsigned short)(vy[j] >> 16));
      s += l1 * l1 + h1 * h1 + l2 * l2 + h2 * h2;
    }
  }
  outp[row] = s * L2E2;   // exp2-domain
}

// ---------------- fused Wasserstein attention: T15 pipeline, 4-wave blocks,
// ---------------- 4 buffers, depth-2 prefetch, unroll-2 ping-pong S ----------------
// (unchanged from R18 -- the proven best attn configuration)
__global__ __launch_bounds__(256, 2) void attn_k(
    const short* __restrict__ Qm, const short* __restrict__ Km, const short* __restrict__ VmT,
    const short* __restrict__ Qs, const short* __restrict__ Ks, const short* __restrict__ VsT,
    const float* __restrict__ sqq, const float* __restrict__ sqk,
    short* __restrict__ Om, short* __restrict__ Os) {
  int id = blockIdx.y * 8 + blockIdx.x;   // gridDim (8,64), 512 blocks
  int pid = id >> 3;                      // 0..63
  int bh = (id & 7) * 4 + (pid >> 4);     // XCD (id&7) owns 4 heads
  int q0 = (pid & 15) * 128;
  int tid = threadIdx.x, w = tid >> 6, ln = tid & 63;
  int l31 = ln & 31, h = ln >> 5;

  // 4 buffers x 16KB: per buffer [0,4K) Km[32r][128B] | [4K,8K) Ks | [8K,16K) V[64r][128B]
  __shared__ __align__(16) char pool[65536];
  short* poolS = (short*)pool;

  const size_t bhQ = (size_t)bh * LSEQ * DK;

  // Q fragments (B operand: col = q = l31, k-dim d = dblk*16 + h*8 + j)
  int q = q0 + w * 32 + l31;
  bf16x8 qmf[4], qsf[4];
#pragma unroll
  for (int d = 0; d < 4; ++d) {
    qmf[d] = *(const bf16x8*)(Qm + bhQ + (size_t)q * DK + d * 16 + h * 8);
    qsf[d] = *(const bf16x8*)(Qs + bhQ + (size_t)q * DK + d * 16 + h * 8);
  }
  float sqQ = sqq[(size_t)bh * LSEQ + q];
  const float* sqkp = sqk + (size_t)bh * LSEQ;

  // staging: 4 x 16B DMA per thread per tile (Km, Ks, V-lower, V-upper).
  int rrK = tid >> 3;                                  // 0..31
  int csK = ((tid & 7) ^ (rrK & 7) ^ ((rrK >> 3) & 3)) * 8;
  const short* sKm = Km + bhQ + (size_t)rrK * DK + csK;
  const short* sKs = Ks + bhQ + (size_t)rrK * DK + csK;
  int rv = tid >> 3;                                   // V rows rv and rv+32
  int cv = (tid & 7) ^ (rv & 7);                       // same for rv+32 (32%8==0)
  const short* sV0 = (cv < 4) ? (VmT + ((size_t)bh * DK + rv) * LSEQ + cv * 8)
                              : (VsT + ((size_t)bh * DK + rv) * LSEQ + (cv - 4) * 8);
  const short* sV1 = (cv < 4) ? (VmT + ((size_t)bh * DK + rv + 32) * LSEQ + cv * 8)
                              : (VsT + ((size_t)bh * DK + rv + 32) * LSEQ + (cv - 4) * 8);

  f32x16 acc[4] = {};
  float prs = 0.f;

  const int krow = l31;
  const int kswz = ((krow & 7) ^ ((krow >> 3) & 3)) << 4;
  const int NT = LSEQ / 32;   // 64 tiles

#define ISSUE_TILE(tt, bb) do {                                              \
    GLD_LDS(sKm + (size_t)(tt) * 2048, poolS + (bb) * 8192 + w * 512);       \
    GLD_LDS(sKs + (size_t)(tt) * 2048, poolS + (bb) * 8192 + 2048 + w * 512);\
    GLD_LDS(sV0 + (size_t)(tt) * 32,   poolS + (bb) * 8192 + 4096 + w * 512);\
    GLD_LDS(sV1 + (size_t)(tt) * 32,   poolS + (bb) * 8192 + 6144 + w * 512);\
  } while (0)

  // merged QK (mu chained into sigma, one f32x16 accumulator)
#define QK_TILE(bb, sdst) do {                                               \
    const char* kb_ = (const char*)(poolS + (bb) * 8192);                    \
    __builtin_amdgcn_s_setprio(1);                                           \
    _Pragma("unroll")                                                        \
    for (int d = 0; d < 4; ++d) {                                            \
      bf16x8 am = *(const bf16x8*)(kb_ + krow * 128 + ((d * 32 + h * 16) ^ kswz)); \
      sdst = MFMA32(am, qmf[d], sdst);                                       \
      bf16x8 as = *(const bf16x8*)(kb_ + 4096 + krow * 128 + ((d * 32 + h * 16) ^ kswz)); \
      sdst = MFMA32(as, qsf[d], sdst);                                       \
    }                                                                        \
    __builtin_amdgcn_s_setprio(0);                                           \
  } while (0)

  // one pipeline step: tile T lands, QK(T)->sCUR, softmax+PV of T-1 from sPREV
#define STEP(T, sCUR, sPREV) do {                                            \
    asm volatile("s_waitcnt vmcnt(8)" ::: "memory");                         \
    asm volatile("s_barrier" ::: "memory");                                  \
    {                                                                        \
      int tn = ((T) + 2 < NT) ? (T) + 2 : (NT - 1);                          \
      ISSUE_TILE(tn, ((T) + 2) & 3);                                         \
    }                                                                        \
    sCUR = (f32x16){};                                                       \
    QK_TILE((T) & 3, sCUR);                                                  \
    float pv[16];                                                            \
    _Pragma("unroll")                                                        \
    for (int rq = 0; rq < 4; ++rq) {                                         \
      _Pragma("unroll")                                                      \
      for (int r = 0; r < 4; ++r) {                                          \
        int i = rq * 4 + r;                                                  \
        float w2 = fmaf(-2.f * L2E2, sPREV[i], rskreg[rq][r]);               \
        float wdp = __builtin_amdgcn_sqrtf(fmaxf(w2, 0.f));                  \
        float sim = fexp2n(wdp);                                             \
        float p = fexp2(sim * L2E);                                          \
        prs += p;                                                            \
        pv[i] = p;                                                           \
      }                                                                      \
    }                                                                        \
    unsigned u0 = cvtpk(pv[0], pv[1]),   u1 = cvtpk(pv[2], pv[3]);           \
    unsigned u2 = cvtpk(pv[4], pv[5]),   u3 = cvtpk(pv[6], pv[7]);           \
    unsigned u4 = cvtpk(pv[8], pv[9]),   u5 = cvtpk(pv[10], pv[11]);         \
    unsigned u6 = cvtpk(pv[12], pv[13]), u7 = cvtpk(pv[14], pv[15]);         \
    asm volatile("v_permlane32_swap_b32 %0, %1" : "+v"(u0), "+v"(u2));       \
    asm volatile("v_permlane32_swap_b32 %0, %1" : "+v"(u1), "+v"(u3));       \
    asm volatile("v_permlane32_swap_b32 %0, %1" : "+v"(u4), "+v"(u6));       \
    asm volatile("v_permlane32_swap_b32 %0, %1" : "+v"(u5), "+v"(u7));       \
    union { uint4 u; bf16x8 v; } f0, f1;                                     \
    f0.u.x = u0; f0.u.y = u1; f0.u.z = u2; f0.u.w = u3;                      \
    f1.u.x = u4; f1.u.y = u5; f1.u.z = u6; f1.u.w = u7;                      \
    _Pragma("unroll")                                                        \
    for (int rq = 0; rq < 4; ++rq) {                                         \
      rskreg[rq] = *(const f32x4*)&sqkp[(T) * 32 + 8 * rq + 4 * h];          \
      _Pragma("unroll")                                                      \
      for (int r = 0; r < 4; ++r) rskreg[rq][r] += sqQ;                      \
    }                                                                        \
    {                                                                        \
      const char* vb = (const char*)(poolS + (((T) - 1) & 3) * 8192) + 8192; \
      __builtin_amdgcn_s_setprio(1);                                         \
      _Pragma("unroll")                                                      \
      for (int vblk = 0; vblk < 4; ++vblk) {                                 \
        int row = (vblk & 1) * 32 + l31;                                     \
        int cb = (vblk >> 1) * 4;                                            \
        int sw = row & 7;                                                    \
        const char* rb = vb + row * 128;                                     \
        bf16x8 v0 = *(const bf16x8*)(rb + (((cb + h) ^ sw) << 4));           \
        bf16x8 v1 = *(const bf16x8*)(rb + (((cb + 2 + h) ^ sw) << 4));       \
        acc[vblk] = MFMA32(v0, f0.v, acc[vblk]);                             \
        acc[vblk] = MFMA32(v1, f1.v, acc[vblk]);                             \
      }                                                                      \
      __builtin_amdgcn_s_setprio(0);                                         \
    }                                                                        \
  } while (0)

  // prolog: issue tiles 0,1; land tile 0 (tile 1 in flight); issue tile 2;
  // QK(0) -> sA; rsk(0)+sqQ
  ISSUE_TILE(0, 0);
  ISSUE_TILE(1, 1);
  asm volatile("s_waitcnt vmcnt(4)" ::: "memory");
  asm volatile("s_barrier" ::: "memory");
  ISSUE_TILE(2, 2);

  f32x16 sA = {}, sB;
  QK_TILE(0, sA);
  f32x4 rskreg[4];
#pragma unroll
  for (int rq = 0; rq < 4; ++rq) {
    rskreg[rq] = *(const f32x4*)&sqkp[8 * rq + 4 * h];
#pragma unroll
    for (int r = 0; r < 4; ++r) rskreg[rq][r] += sqQ;
  }

  // pairs t = (1,2), (3,4), ..., (61,62); then t = 63 single
  for (int t = 1; t + 1 < NT; t += 2) {
    STEP(t, sB, sA);        // QK(t)->sB, softmax/PV of t-1 from sA
    STEP(t + 1, sA, sB);    // QK(t+1)->sA, softmax/PV of t from sB
  }
  STEP(NT - 1, sB, sA);     // QK(63)->sB, softmax/PV of 62 from sA

  asm volatile("s_waitcnt vmcnt(0)" ::: "memory");   // drain clamped DMAs

  // tail: softmax + PV of tile NT-1 (sB; rskreg = rsk(NT-1)+sqQ)
  {
    float pv[16];
#pragma unroll
    for (int rq = 0; rq < 4; ++rq) {
#pragma unroll
      for (int r = 0; r < 4; ++r) {
        int i = rq * 4 + r;
        float w2 = fmaf(-2.f * L2E2, sB[i], rskreg[rq][r]);
        float wdp = __builtin_amdgcn_sqrtf(fmaxf(w2, 0.f));
        float sim = fexp2n(wdp);
        float p = fexp2(sim * L2E);
        prs += p;
        pv[i] = p;
      }
    }
    unsigned u0 = cvtpk(pv[0], pv[1]),   u1 = cvtpk(pv[2], pv[3]);
    unsigned u2 = cvtpk(pv[4], pv[5]),   u3 = cvtpk(pv[6], pv[7]);
    unsigned u4 = cvtpk(pv[8], pv[9]),   u5 = cvtpk(pv[10], pv[11]);
    unsigned u6 = cvtpk(pv[12], pv[13]), u7 = cvtpk(pv[14], pv[15]);
    asm volatile("v_permlane32_swap_b32 %0, %1" : "+v"(u0), "+v"(u2));
    asm volatile("v_permlane32_swap_b32 %0, %1" : "+v"(u1), "+v"(u3));
    asm volatile("v_permlane32_swap_b32 %0, %1" : "+v"(u4), "+v"(u6));
    asm volatile("v_permlane32_swap_b32 %0, %1" : "+v"(u5), "+v"(u7));
    union { uint4 u; bf16x8 v; } f0, f1;
    f0.u.x = u0; f0.u.y = u1; f0.u.z = u2; f0.u.w = u3;
    f1.u.x = u4; f1.u.y = u5; f1.u.z = u6; f1.u.w = u7;

    const char* vb = (const char*)(poolS + ((NT - 1) & 3) * 8192) + 8192;
#pragma unroll
    for (int vblk = 0; vblk < 4; ++vblk) {
      int row = (vblk & 1) * 32 + l31;
      int cb = (vblk >> 1) * 4;
      int sw = row & 7;
      const char* rb = vb + row * 128;
      bf16x8 v0 = *(const bf16x8*)(rb + (((cb + h) ^ sw) << 4));
      bf16x8 v1 = *(const bf16x8*)(rb + (((cb + 2 + h) ^ sw) << 4));
      acc[vblk] = MFMA32(v0, f0.v, acc[vblk]);
      acc[vblk] = MFMA32(v1, f1.v, acc[vblk]);
    }
  }

  // row-sum: reduce over lane halves (h split of k-rows)
  prs += __shfl_xor(prs, 32);
  float inv = 1.f / prs;

  int b = bh >> 4, hh = bh & 15;
  size_t orow = ((size_t)(b * LSEQ + q)) * DMODEL + hh * DK;
#pragma unroll
  for (int vblk = 0; vblk < 4; ++vblk) {
    short* obuf = (vblk < 2) ? Om : Os;
    int vbase = (vblk & 1) * 32 + 4 * h;
#pragma unroll
    for (int rq = 0; rq < 4; ++rq) {
      float o0 = acc[vblk][rq * 4 + 0] * inv;
      float o1 = acc[vblk][rq * 4 + 1] * inv;
      float o2 = acc[vblk][rq * 4 + 2] * inv;
      float o3 = acc[vblk][rq * 4 + 3] * inv;
      uint2 pk; pk.x = pk2c(o0, o1); pk.y = pk2c(o2, o3);
      *(uint2*)(obuf + orow + vbase + 8 * rq) = pk;
    }
  }
#undef ISSUE_TILE
#undef QK_TILE
#undef STEP
}

extern "C" void kernel_launch(void* const* d_in, const int* in_sizes, int n_in,
                              void* d_out, int out_size, void* d_ws, size_t ws_size,
                              hipStream_t stream) {
  const float* mu    = (const float*)d_in[0];
  const float* sigma = (const float*)d_in[1];
  const float* Wqm   = (const float*)d_in[2];
  const float* bqm   = (const float*)d_in[3];
  const float* Wqs   = (const float*)d_in[4];
  const float* bqs   = (const float*)d_in[5];
  const float* Wo    = (const float*)d_in[6];
  const float* bo    = (const float*)d_in[7];
  float* out = (float*)d_out;
  char* ws = (char*)d_ws;
  const size_t MB = 1u << 20;

  short* Amu   = (short*)(ws + 0);        // 8MB, reused as Om
  short* Asg   = (short*)(ws + 8 * MB);   // 8MB, reused as Os (contiguous with Om)
  short* Wqm_t = (short*)(ws + 16 * MB);  // 6MB
  short* Wqs_t = (short*)(ws + 22 * MB);  // 6MB
  short* Wo_t  = (short*)(ws + 28 * MB);  // 2MB
  short* Qm    = (short*)(ws + 30 * MB);  // 8MB each below
  short* Km    = (short*)(ws + 38 * MB);
  short* VmT   = (short*)(ws + 46 * MB);
  short* Qs    = (short*)(ws + 54 * MB);
  short* Ks    = (short*)(ws + 62 * MB);
  short* VsT   = (short*)(ws + 70 * MB);
  float* sqq   = (float*)(ws + 78 * MB);            // 256KB
  float* sqk   = (float*)(ws + 78 * MB + 256 * 1024);
  short* Om = Amu;
  short* Os = Asg;

  cvt_all_k<<<9216, 256, 0, stream>>>(mu, sigma, Amu, Asg,
                                      Wqm, Wqs, Wo, Wqm_t, Wqs_t, Wo_t);

  // grid transposed: x = ny (-> XCD = ny%8, B-panels L2-resident), y = m
  qkv_gemm_k<<<dim3(48, 32), 256, 0, stream>>>(Amu, Asg, Wqm_t, Wqs_t, bqm, bqs,
                                               Qm, Km, VmT, Qs, Ks, VsT);

  norms_k<<<512, 256, 0, stream>>>(Qm, Qs, Km, Ks, sqq, sqk);

  attn_k<<<dim3(8, 64), 256, 0, stream>>>(Qm, Km, VmT, Qs, Ks, VsT, sqq, sqk, Om, Os);

  // out-proj for mu and sigma as ONE GEMM (Om|Os contiguous, M=8192)
  gemm128_k<<<dim3(64, 8), 256, 0, stream>>>(Om, Wo_t, bo, out);
}

// Round 20
// 222.151 us; speedup vs baseline: 1.0119x; 1.0119x over previous
//
#include <hip/hip_runtime.h>
#include <hip/hip_bf16.h>

#define LSEQ   2048
#define DK     64
#define NH     16
#define BS     2
#define DMODEL 1024
#define BH     (BS*NH)    // 32
#define MTOT   (BS*LSEQ)  // 4096

typedef __attribute__((ext_vector_type(8))) short bf16x8;
typedef __attribute__((ext_vector_type(4))) float f32x4;
typedef __attribute__((ext_vector_type(16))) float f32x16;

#define MFMA16(a,b,c) __builtin_amdgcn_mfma_f32_16x16x32_bf16((a),(b),(c),0,0,0)
#define MFMA32(a,b,c) __builtin_amdgcn_mfma_f32_32x32x16_bf16((a),(b),(c),0,0,0)
#define GLD_LDS(g,l) __builtin_amdgcn_global_load_lds((const __attribute__((address_space(1))) void*)(g), (__attribute__((address_space(3))) void*)(l), 16, 0, 0)

#define L2E   1.4426950408889634f      // log2(e)
#define L2E2  2.0813689810056077f      // log2(e)^2

__device__ __forceinline__ short f2bs(float f) {
  union { __hip_bfloat16 h; short s; } u; u.h = __float2bfloat16(f); return u.s;
}
__device__ __forceinline__ float b2f(unsigned short s) {
  union { unsigned u; float f; } v; v.u = ((unsigned)s) << 16; return v.f;
}
// cheap round-half-up bf16 (inputs guaranteed finite)
__device__ __forceinline__ unsigned short f2bs_c(float f) {
  union { float f; unsigned u; } v; v.f = f;
  return (unsigned short)((v.u + 0x8000u) >> 16);
}
__device__ __forceinline__ unsigned pk2c(float lo, float hi) {
  union { float f; unsigned u; } a, b; a.f = lo; b.f = hi;
  return ((a.u + 0x8000u) >> 16) | ((b.u + 0x8000u) & 0xffff0000u);
}
__device__ __forceinline__ unsigned pk2(float lo, float hi) {
  return (unsigned)(unsigned short)f2bs(lo) | (((unsigned)(unsigned short)f2bs(hi)) << 16);
}
// raw v_exp_f32 (2^x); VALU->VALU deps are HW-interlocked on CDNA
__device__ __forceinline__ float fexp2(float x) {
  float r; asm("v_exp_f32 %0, %1" : "=v"(r) : "v"(x)); return r;
}
__device__ __forceinline__ float fexp2n(float x) {   // 2^(-x), free input modifier
  float r; asm("v_exp_f32 %0, -%1" : "=v"(r) : "v"(x)); return r;
}
// single-instruction packed f32->bf16 (RNE)
__device__ __forceinline__ unsigned cvtpk(float lo, float hi) {
  unsigned r; asm("v_cvt_pk_bf16_f32 %0, %1, %2" : "=v"(r) : "v"(lo), "v"(hi)); return r;
}

// ---------------- fused converts: weight transposes + activations ----------------
// blocks 0..7167: f32 [K][N] -> bf16 [N][K] transposes (Wqm 3072, Wqs 3072, Wo 1024)
// blocks 7168..9215: flat f32 -> bf16 convert of mu|sigma (grid-stride, 2048 blocks)
__global__ __launch_bounds__(256) void cvt_all_k(
    const float* __restrict__ mu, const float* __restrict__ sigma,
    short* __restrict__ Amu, short* __restrict__ Asg,
    const float* __restrict__ Wqm, const float* __restrict__ Wqs, const float* __restrict__ Wo,
    short* __restrict__ Wqm_t, short* __restrict__ Wqs_t, short* __restrict__ Wo_t) {
  int id = blockIdx.x;
  int t = threadIdx.x;
  if (id >= 7168) {
    int n8 = MTOT * DMODEL / 8;
    int total = n8 * 2;
    for (int i = (id - 7168) * 256 + t; i < total; i += 2048 * 256) {
      int sel = i >= n8;
      int j = sel ? i - n8 : i;
      const float4* p = (const float4*)(sel ? sigma : mu) + (size_t)j * 2;
      float4 x = p[0], y = p[1];
      uint4 o;
      o.x = pk2(x.x, x.y); o.y = pk2(x.z, x.w);
      o.z = pk2(y.x, y.y); o.w = pk2(y.z, y.w);
      ((uint4*)(sel ? Asg : Amu))[j] = o;
    }
    return;
  }
  __shared__ float tile[32][33];
  const float* W; short* Wt; int Ncols, bx;
  if (id < 3072)      { W = Wqm; Wt = Wqm_t; Ncols = 3072; bx = id % 96; id /= 96; }
  else if (id < 6144) { id -= 3072; W = Wqs; Wt = Wqs_t; Ncols = 3072; bx = id % 96; id /= 96; }
  else                { id -= 6144; W = Wo;  Wt = Wo_t;  Ncols = 1024; bx = id % 32; id /= 32; }
  int n0 = bx * 32, k0 = id * 32;
#pragma unroll
  for (int i = 0; i < 4; ++i) {
    int idx = t + i * 256; int r = idx >> 5, c = idx & 31;
    tile[r][c] = W[(size_t)(k0 + r) * Ncols + n0 + c];
  }
  __syncthreads();
#pragma unroll
  for (int i = 0; i < 4; ++i) {
    int idx = t + i * 256; int r = idx >> 5, c = idx & 31;
    Wt[(size_t)(n0 + r) * 1024 + k0 + c] = f2bs(tile[c][r]);
  }
}

// ---------------- fused QKV GEMM (mu + sigma in ONE dispatch), 128x128 tile ----------------
__global__ __launch_bounds__(256) void qkv_gemm_k(
    const short* __restrict__ Amu, const short* __restrict__ Asg,
    const short* __restrict__ Wqm_t, const short* __restrict__ Wqs_t,
    const float* __restrict__ bqm, const float* __restrict__ bqs,
    short* __restrict__ Qm, short* __restrict__ Km, short* __restrict__ VmT,
    short* __restrict__ Qs, short* __restrict__ Ks, short* __restrict__ VsT) {
  __shared__ short As[128 * 64];
  __shared__ short Bs[128 * 64];
  int ny = blockIdx.y;                 // 0..47; >=24 -> sigma set
  int sg = ny >= 24;
  int n0 = (sg ? ny - 24 : ny) * 128;
  const short* A  = sg ? Asg : Amu;
  const short* Bt = sg ? Wqs_t : Wqm_t;
  const float* bias = sg ? bqs : bqm;
  short* Qb  = sg ? Qs : Qm;
  short* Kb  = sg ? Ks : Km;
  short* VTb = sg ? VsT : VmT;

  int tid = threadIdx.x, w = tid >> 6, ln = tid & 63, lg = ln >> 4, lr = ln & 15;
  int m0 = blockIdx.x * 128;
  int wr = w >> 1, wc = w & 1;
  f32x4 acc[4][4] = {};

  for (int k0 = 0; k0 < 1024; k0 += 64) {
    __syncthreads();
#pragma unroll
    for (int i = 0; i < 4; ++i) {
      int cb = w * 64 + i * 256;
      int c = cb + ln;
      GLD_LDS(A  + (size_t)(m0 + (c >> 3)) * 1024 + k0 + (c & 7) * 8, &As[cb * 8]);
      GLD_LDS(Bt + (size_t)(n0 + (c >> 3)) * 1024 + k0 + (c & 7) * 8, &Bs[cb * 8]);
    }
    __syncthreads();
#pragma unroll
    for (int kh = 0; kh < 2; ++kh) {
      bf16x8 af[4], bfr[4];
#pragma unroll
      for (int mi = 0; mi < 4; ++mi)
        af[mi] = *(const bf16x8*)&As[(wr * 64 + mi * 16 + lr) * 64 + kh * 32 + lg * 8];
#pragma unroll
      for (int ni = 0; ni < 4; ++ni)
        bfr[ni] = *(const bf16x8*)&Bs[(wc * 64 + ni * 16 + lr) * 64 + kh * 32 + lg * 8];
#pragma unroll
      for (int mi = 0; mi < 4; ++mi)
#pragma unroll
        for (int ni = 0; ni < 4; ++ni)
          acc[mi][ni] = MFMA16(af[mi], bfr[ni], acc[mi][ni]);
    }
  }

#pragma unroll
  for (int ni = 0; ni < 4; ++ni) {
    int n = n0 + wc * 64 + ni * 16 + lr;
    float bv = bias[n];
    int part = n >> 10, cc = n & 1023, hh = cc >> 6, dd = cc & 63;
#pragma unroll
    for (int mi = 0; mi < 4; ++mi) {
      int mbase = m0 + wr * 64 + mi * 16 + 4 * lg;
      float vv[4];
#pragma unroll
      for (int r = 0; r < 4; ++r) vv[r] = acc[mi][ni][r] + bv;
      if (part == 2) {
        int b = mbase >> 11, tok = mbase & 2047, bh = b * NH + hh;
        uint2 pk; pk.x = pk2c(vv[0], vv[1]); pk.y = pk2c(vv[2], vv[3]);
        *(uint2*)&VTb[((size_t)bh * DK + dd) * LSEQ + tok] = pk;
      } else {
        short* dst = (part == 0) ? Qb : Kb;
#pragma unroll
        for (int r = 0; r < 4; ++r) {
          int m = mbase + r;
          int b = m >> 11, tok = m & 2047, bh = b * NH + hh;
          dst[((size_t)bh * LSEQ + tok) * DK + dd] = (short)f2bs_c(vv[r]);
        }
      }
    }
  }
}

// ---------------- 128x128-tile bf16 GEMM (out-proj, f32 out) ----------------
__global__ __launch_bounds__(256) void gemm128_k(
    const short* __restrict__ A, const short* __restrict__ Bt,
    const float* __restrict__ bias, float* __restrict__ outF) {
  __shared__ short As[128 * 64];
  __shared__ short Bs[128 * 64];
  int tid = threadIdx.x, w = tid >> 6, ln = tid & 63, lg = ln >> 4, lr = ln & 15;
  int m0 = blockIdx.x * 128, n0 = blockIdx.y * 128;
  int wr = w >> 1, wc = w & 1;
  f32x4 acc[4][4] = {};

  for (int k0 = 0; k0 < 1024; k0 += 64) {
    __syncthreads();
#pragma unroll
    for (int i = 0; i < 4; ++i) {
      int cb = w * 64 + i * 256;
      int c = cb + ln;
      GLD_LDS(A  + (size_t)(m0 + (c >> 3)) * 1024 + k0 + (c & 7) * 8, &As[cb * 8]);
      GLD_LDS(Bt + (size_t)(n0 + (c >> 3)) * 1024 + k0 + (c & 7) * 8, &Bs[cb * 8]);
    }
    __syncthreads();
#pragma unroll
    for (int kh = 0; kh < 2; ++kh) {
      bf16x8 af[4], bfr[4];
#pragma unroll
      for (int mi = 0; mi < 4; ++mi)
        af[mi] = *(const bf16x8*)&As[(wr * 64 + mi * 16 + lr) * 64 + kh * 32 + lg * 8];
#pragma unroll
      for (int ni = 0; ni < 4; ++ni)
        bfr[ni] = *(const bf16x8*)&Bs[(wc * 64 + ni * 16 + lr) * 64 + kh * 32 + lg * 8];
#pragma unroll
      for (int mi = 0; mi < 4; ++mi)
#pragma unroll
        for (int ni = 0; ni < 4; ++ni)
          acc[mi][ni] = MFMA16(af[mi], bfr[ni], acc[mi][ni]);
    }
  }

#pragma unroll
  for (int ni = 0; ni < 4; ++ni) {
    int n = n0 + wc * 64 + ni * 16 + lr;
    float bv = bias[n];
#pragma unroll
    for (int mi = 0; mi < 4; ++mi) {
      int mbase = m0 + wr * 64 + mi * 16 + 4 * lg;
#pragma unroll
      for (int r = 0; r < 4; ++r)
        outF[(size_t)(mbase + r) * 1024 + n] = acc[mi][ni][r] + bv;
    }
  }
}

// ---------------- per-row squared norms (pre-scaled by log2(e)^2) ----------------
__global__ __launch_bounds__(256) void norms_k(
    const short* __restrict__ Qm, const short* __restrict__ Qs,
    const short* __restrict__ Km, const short* __restrict__ Ks,
    float* __restrict__ sqq, float* __restrict__ sqk) {
  int id = blockIdx.x * 256 + threadIdx.x;  // 0..131071
  int row = id & 65535;
  const short* p1 = (id < 65536) ? Qm : Km;
  const short* p2 = (id < 65536) ? Qs : Ks;
  float* outp = (id < 65536) ? sqq : sqk;
  const uint4* a = (const uint4*)(p1 + (size_t)row * DK);
  const uint4* b = (const uint4*)(p2 + (size_t)row * DK);
  float s = 0.f;
#pragma unroll
  for (int i = 0; i < 8; ++i) {
    uint4 x = a[i], y = b[i];
    unsigned vx[4] = {x.x, x.y, x.z, x.w};
    unsigned vy[4] = {y.x, y.y, y.z, y.w};
#pragma unroll
    for (int j = 0; j < 4; ++j) {
      float l1 = b2f((unsigned short)(vx[j] & 0xffff)), h1 = b2f((unsigned short)(vx[j] >> 16));
      float l2 = b2f((unsigned short)(vy[j] & 0xffff)), h2 = b2f((unsigned short)(vy[j] >> 16));
      s += l1 * l1 + h1 * h1 + l2 * l2 + h2 * h2;
    }
  }
  outp[row] = s * L2E2;   // exp2-domain
}

// ---------------- fused Wasserstein attention: T15 pipeline, 4-wave blocks,
// ---------------- 4 buffers, depth-2 prefetch, unroll-2 ping-pong S ----------------
// R20: V swizzle upgraded to the R8-proven two-term form
// swz(row) = (row&7) ^ ((row>>3)&3) on BOTH the DMA source and the read
// (rule #21) -- R14+'s single-term (row&7) left 16-lane phase groups with
// slot aliasing (SQ_LDS_BANK_CONFLICT constant 2^22 since R13; K path with
// the two-term swizzle measured 0 in R8-R12).
__global__ __launch_bounds__(256, 2) void attn_k(
    const short* __restrict__ Qm, const short* __restrict__ Km, const short* __restrict__ VmT,
    const short* __restrict__ Qs, const short* __restrict__ Ks, const short* __restrict__ VsT,
    const float* __restrict__ sqq, const float* __restrict__ sqk,
    short* __restrict__ Om, short* __restrict__ Os) {
  int id = blockIdx.y * 8 + blockIdx.x;   // gridDim (8,64), 512 blocks
  int pid = id >> 3;                      // 0..63
  int bh = (id & 7) * 4 + (pid >> 4);     // XCD (id&7) owns 4 heads
  int q0 = (pid & 15) * 128;
  int tid = threadIdx.x, w = tid >> 6, ln = tid & 63;
  int l31 = ln & 31, h = ln >> 5;

  // 4 buffers x 16KB: per buffer [0,4K) Km[32r][128B] | [4K,8K) Ks | [8K,16K) V[64r][128B]
  __shared__ __align__(16) char pool[65536];
  short* poolS = (short*)pool;

  const size_t bhQ = (size_t)bh * LSEQ * DK;

  // Q fragments (B operand: col = q = l31, k-dim d = dblk*16 + h*8 + j)
  int q = q0 + w * 32 + l31;
  bf16x8 qmf[4], qsf[4];
#pragma unroll
  for (int d = 0; d < 4; ++d) {
    qmf[d] = *(const bf16x8*)(Qm + bhQ + (size_t)q * DK + d * 16 + h * 8);
    qsf[d] = *(const bf16x8*)(Qs + bhQ + (size_t)q * DK + d * 16 + h * 8);
  }
  float sqQ = sqq[(size_t)bh * LSEQ + q];
  const float* sqkp = sqk + (size_t)bh * LSEQ;

  // staging: 4 x 16B DMA per thread per tile (Km, Ks, V-lower, V-upper).
  int rrK = tid >> 3;                                  // 0..31
  int csK = ((tid & 7) ^ (rrK & 7) ^ ((rrK >> 3) & 3)) * 8;
  const short* sKm = Km + bhQ + (size_t)rrK * DK + csK;
  const short* sKs = Ks + bhQ + (size_t)rrK * DK + csK;
  int rv = tid >> 3;                                   // V rows rv and rv+32
  // two-term swizzle; identical for rv and rv+32 since ((rv+32)>>3)&3 == (rv>>3)&3
  int cv = (tid & 7) ^ (rv & 7) ^ ((rv >> 3) & 3);
  const short* sV0 = (cv < 4) ? (VmT + ((size_t)bh * DK + rv) * LSEQ + cv * 8)
                              : (VsT + ((size_t)bh * DK + rv) * LSEQ + (cv - 4) * 8);
  const short* sV1 = (cv < 4) ? (VmT + ((size_t)bh * DK + rv + 32) * LSEQ + cv * 8)
                              : (VsT + ((size_t)bh * DK + rv + 32) * LSEQ + (cv - 4) * 8);

  f32x16 acc[4] = {};
  float prs = 0.f;

  const int krow = l31;
  const int kswz = ((krow & 7) ^ ((krow >> 3) & 3)) << 4;
  const int NT = LSEQ / 32;   // 64 tiles

#define ISSUE_TILE(tt, bb) do {                                              \
    GLD_LDS(sKm + (size_t)(tt) * 2048, poolS + (bb) * 8192 + w * 512);       \
    GLD_LDS(sKs + (size_t)(tt) * 2048, poolS + (bb) * 8192 + 2048 + w * 512);\
    GLD_LDS(sV0 + (size_t)(tt) * 32,   poolS + (bb) * 8192 + 4096 + w * 512);\
    GLD_LDS(sV1 + (size_t)(tt) * 32,   poolS + (bb) * 8192 + 6144 + w * 512);\
  } while (0)

  // merged QK (mu chained into sigma, one f32x16 accumulator)
#define QK_TILE(bb, sdst) do {                                               \
    const char* kb_ = (const char*)(poolS + (bb) * 8192);                    \
    __builtin_amdgcn_s_setprio(1);                                           \
    _Pragma("unroll")                                                        \
    for (int d = 0; d < 4; ++d) {                                            \
      bf16x8 am = *(const bf16x8*)(kb_ + krow * 128 + ((d * 32 + h * 16) ^ kswz)); \
      sdst = MFMA32(am, qmf[d], sdst);                                       \
      bf16x8 as = *(const bf16x8*)(kb_ + 4096 + krow * 128 + ((d * 32 + h * 16) ^ kswz)); \
      sdst = MFMA32(as, qsf[d], sdst);                                       \
    }                                                                        \
    __builtin_amdgcn_s_setprio(0);                                           \
  } while (0)

  // one pipeline step: tile T lands, QK(T)->sCUR, softmax+PV of T-1 from sPREV
#define STEP(T, sCUR, sPREV) do {                                            \
    asm volatile("s_waitcnt vmcnt(8)" ::: "memory");                         \
    asm volatile("s_barrier" ::: "memory");                                  \
    {                                                                        \
      int tn = ((T) + 2 < NT) ? (T) + 2 : (NT - 1);                          \
      ISSUE_TILE(tn, ((T) + 2) & 3);                                         \
    }                                                                        \
    sCUR = (f32x16){};                                                       \
    QK_TILE((T) & 3, sCUR);                                                  \
    float pv[16];                                                            \
    _Pragma("unroll")                                                        \
    for (int rq = 0; rq < 4; ++rq) {                                         \
      _Pragma("unroll")                                                      \
      for (int r = 0; r < 4; ++r) {                                          \
        int i = rq * 4 + r;                                                  \
        float w2 = fmaf(-2.f * L2E2, sPREV[i], rskreg[rq][r]);               \
        float wdp = __builtin_amdgcn_sqrtf(fmaxf(w2, 0.f));                  \
        float sim = fexp2n(wdp);                                             \
        float p = fexp2(sim * L2E);                                          \
        prs += p;                                                            \
        pv[i] = p;                                                           \
      }                                                                      \
    }                                                                        \
    unsigned u0 = cvtpk(pv[0], pv[1]),   u1 = cvtpk(pv[2], pv[3]);           \
    unsigned u2 = cvtpk(pv[4], pv[5]),   u3 = cvtpk(pv[6], pv[7]);           \
    unsigned u4 = cvtpk(pv[8], pv[9]),   u5 = cvtpk(pv[10], pv[11]);         \
    unsigned u6 = cvtpk(pv[12], pv[13]), u7 = cvtpk(pv[14], pv[15]);         \
    asm volatile("v_permlane32_swap_b32 %0, %1" : "+v"(u0), "+v"(u2));       \
    asm volatile("v_permlane32_swap_b32 %0, %1" : "+v"(u1), "+v"(u3));       \
    asm volatile("v_permlane32_swap_b32 %0, %1" : "+v"(u4), "+v"(u6));       \
    asm volatile("v_permlane32_swap_b32 %0, %1" : "+v"(u5), "+v"(u7));       \
    union { uint4 u; bf16x8 v; } f0, f1;                                     \
    f0.u.x = u0; f0.u.y = u1; f0.u.z = u2; f0.u.w = u3;                      \
    f1.u.x = u4; f1.u.y = u5; f1.u.z = u6; f1.u.w = u7;                      \
    _Pragma("unroll")                                                        \
    for (int rq = 0; rq < 4; ++rq) {                                         \
      rskreg[rq] = *(const f32x4*)&sqkp[(T) * 32 + 8 * rq + 4 * h];          \
      _Pragma("unroll")                                                      \
      for (int r = 0; r < 4; ++r) rskreg[rq][r] += sqQ;                      \
    }                                                                        \
    {                                                                        \
      const char* vb = (const char*)(poolS + (((T) - 1) & 3) * 8192) + 8192; \
      __builtin_amdgcn_s_setprio(1);                                         \
      _Pragma("unroll")                                                      \
      for (int vblk = 0; vblk < 4; ++vblk) {                                 \
        int row = (vblk & 1) * 32 + l31;                                     \
        int cb = (vblk >> 1) * 4;                                            \
        int sw = (row & 7) ^ ((row >> 3) & 3);                               \
        const char* rb = vb + row * 128;                                     \
        bf16x8 v0 = *(const bf16x8*)(rb + (((cb + h) ^ sw) << 4));           \
        bf16x8 v1 = *(const bf16x8*)(rb + (((cb + 2 + h) ^ sw) << 4));       \
        acc[vblk] = MFMA32(v0, f0.v, acc[vblk]);                             \
        acc[vblk] = MFMA32(v1, f1.v, acc[vblk]);                             \
      }                                                                      \
      __builtin_amdgcn_s_setprio(0);                                         \
    }                                                                        \
  } while (0)

  // prolog: issue tiles 0,1; land tile 0 (tile 1 in flight); issue tile 2;
  // QK(0) -> sA; rsk(0)+sqQ
  ISSUE_TILE(0, 0);
  ISSUE_TILE(1, 1);
  asm volatile("s_waitcnt vmcnt(4)" ::: "memory");
  asm volatile("s_barrier" ::: "memory");
  ISSUE_TILE(2, 2);

  f32x16 sA = {}, sB;
  QK_TILE(0, sA);
  f32x4 rskreg[4];
#pragma unroll
  for (int rq = 0; rq < 4; ++rq) {
    rskreg[rq] = *(const f32x4*)&sqkp[8 * rq + 4 * h];
#pragma unroll
    for (int r = 0; r < 4; ++r) rskreg[rq][r] += sqQ;
  }

  // pairs t = (1,2), (3,4), ..., (61,62); then t = 63 single
  for (int t = 1; t + 1 < NT; t += 2) {
    STEP(t, sB, sA);        // QK(t)->sB, softmax/PV of t-1 from sA
    STEP(t + 1, sA, sB);    // QK(t+1)->sA, softmax/PV of t from sB
  }
  STEP(NT - 1, sB, sA);     // QK(63)->sB, softmax/PV of 62 from sA

  asm volatile("s_waitcnt vmcnt(0)" ::: "memory");   // drain clamped DMAs

  // tail: softmax + PV of tile NT-1 (sB; rskreg = rsk(NT-1)+sqQ)
  {
    float pv[16];
#pragma unroll
    for (int rq = 0; rq < 4; ++rq) {
#pragma unroll
      for (int r = 0; r < 4; ++r) {
        int i = rq * 4 + r;
        float w2 = fmaf(-2.f * L2E2, sB[i], rskreg[rq][r]);
        float wdp = __builtin_amdgcn_sqrtf(fmaxf(w2, 0.f));
        float sim = fexp2n(wdp);
        float p = fexp2(sim * L2E);
        prs += p;
        pv[i] = p;
      }
    }
    unsigned u0 = cvtpk(pv[0], pv[1]),   u1 = cvtpk(pv[2], pv[3]);
    unsigned u2 = cvtpk(pv[4], pv[5]),   u3 = cvtpk(pv[6], pv[7]);
    unsigned u4 = cvtpk(pv[8], pv[9]),   u5 = cvtpk(pv[10], pv[11]);
    unsigned u6 = cvtpk(pv[12], pv[13]), u7 = cvtpk(pv[14], pv[15]);
    asm volatile("v_permlane32_swap_b32 %0, %1" : "+v"(u0), "+v"(u2));
    asm volatile("v_permlane32_swap_b32 %0, %1" : "+v"(u1), "+v"(u3));
    asm volatile("v_permlane32_swap_b32 %0, %1" : "+v"(u4), "+v"(u6));
    asm volatile("v_permlane32_swap_b32 %0, %1" : "+v"(u5), "+v"(u7));
    union { uint4 u; bf16x8 v; } f0, f1;
    f0.u.x = u0; f0.u.y = u1; f0.u.z = u2; f0.u.w = u3;
    f1.u.x = u4; f1.u.y = u5; f1.u.z = u6; f1.u.w = u7;

    const char* vb = (const char*)(poolS + ((NT - 1) & 3) * 8192) + 8192;
#pragma unroll
    for (int vblk = 0; vblk < 4; ++vblk) {
      int row = (vblk & 1) * 32 + l31;
      int cb = (vblk >> 1) * 4;
      int sw = (row & 7) ^ ((row >> 3) & 3);
      const char* rb = vb + row * 128;
      bf16x8 v0 = *(const bf16x8*)(rb + (((cb + h) ^ sw) << 4));
      bf16x8 v1 = *(const bf16x8*)(rb + (((cb + 2 + h) ^ sw) << 4));
      acc[vblk] = MFMA32(v0, f0.v, acc[vblk]);
      acc[vblk] = MFMA32(v1, f1.v, acc[vblk]);
    }
  }

  // row-sum: reduce over lane halves (h split of k-rows)
  prs += __shfl_xor(prs, 32);
  float inv = 1.f / prs;

  int b = bh >> 4, hh = bh & 15;
  size_t orow = ((size_t)(b * LSEQ + q)) * DMODEL + hh * DK;
#pragma unroll
  for (int vblk = 0; vblk < 4; ++vblk) {
    short* obuf = (vblk < 2) ? Om : Os;
    int vbase = (vblk & 1) * 32 + 4 * h;
#pragma unroll
    for (int rq = 0; rq < 4; ++rq) {
      float o0 = acc[vblk][rq * 4 + 0] * inv;
      float o1 = acc[vblk][rq * 4 + 1] * inv;
      float o2 = acc[vblk][rq * 4 + 2] * inv;
      float o3 = acc[vblk][rq * 4 + 3] * inv;
      uint2 pk; pk.x = pk2c(o0, o1); pk.y = pk2c(o2, o3);
      *(uint2*)(obuf + orow + vbase + 8 * rq) = pk;
    }
  }
#undef ISSUE_TILE
#undef QK_TILE
#undef STEP
}

extern "C" void kernel_launch(void* const* d_in, const int* in_sizes, int n_in,
                              void* d_out, int out_size, void* d_ws, size_t ws_size,
                              hipStream_t stream) {
  const float* mu    = (const float*)d_in[0];
  const float* sigma = (const float*)d_in[1];
  const float* Wqm   = (const float*)d_in[2];
  const float* bqm   = (const float*)d_in[3];
  const float* Wqs   = (const float*)d_in[4];
  const float* bqs   = (const float*)d_in[5];
  const float* Wo    = (const float*)d_in[6];
  const float* bo    = (const float*)d_in[7];
  float* out = (float*)d_out;
  char* ws = (char*)d_ws;
  const size_t MB = 1u << 20;

  short* Amu   = (short*)(ws + 0);        // 8MB, reused as Om
  short* Asg   = (short*)(ws + 8 * MB);   // 8MB, reused as Os (contiguous with Om)
  short* Wqm_t = (short*)(ws + 16 * MB);  // 6MB
  short* Wqs_t = (short*)(ws + 22 * MB);  // 6MB
  short* Wo_t  = (short*)(ws + 28 * MB);  // 2MB
  short* Qm    = (short*)(ws + 30 * MB);  // 8MB each below
  short* Km    = (short*)(ws + 38 * MB);
  short* VmT   = (short*)(ws + 46 * MB);
  short* Qs    = (short*)(ws + 54 * MB);
  short* Ks    = (short*)(ws + 62 * MB);
  short* VsT   = (short*)(ws + 70 * MB);
  float* sqq   = (float*)(ws + 78 * MB);            // 256KB
  float* sqk   = (float*)(ws + 78 * MB + 256 * 1024);
  short* Om = Amu;
  short* Os = Asg;

  cvt_all_k<<<9216, 256, 0, stream>>>(mu, sigma, Amu, Asg,
                                      Wqm, Wqs, Wo, Wqm_t, Wqs_t, Wo_t);

  qkv_gemm_k<<<dim3(32, 48), 256, 0, stream>>>(Amu, Asg, Wqm_t, Wqs_t, bqm, bqs,
                                               Qm, Km, VmT, Qs, Ks, VsT);

  norms_k<<<512, 256, 0, stream>>>(Qm, Qs, Km, Ks, sqq, sqk);

  attn_k<<<dim3(8, 64), 256, 0, stream>>>(Qm, Km, VmT, Qs, Ks, VsT, sqq, sqk, Om, Os);

  // out-proj for mu and sigma as ONE GEMM (Om|Os contiguous, M=8192)
  gemm128_k<<<dim3(64, 8), 256, 0, stream>>>(Om, Wo_t, bo, out);
}